// Round 6
// baseline (269.512 us; speedup 1.0000x reference)
//
#include <hip/hip_runtime.h>
#include <hip/hip_bf16.h>

typedef __bf16 bf16_t;
typedef bf16_t bf16x8 __attribute__((ext_vector_type(8)));
typedef float floatx4 __attribute__((ext_vector_type(4)));
typedef float floatx2 __attribute__((ext_vector_type(2)));

#define N_NODES 100000
#define N_EDGES 1000000

// PQ8 row layout (256 B per node): byte b = h*128 + l15*8 + j  holds fp8 of
// column  h*128 + j*16 + l15   (h = half, l15 = 0..15, j = 0..7).
// Edge kernel lane lg reads bytes lg*8..lg*8+7 of a half -> channels j*16+lg;
// identical mapping for p-half and q-half, wabs permuted to match.

// ---------------- kernel 1: prep ----------------
__global__ __launch_bounds__(256) void k_prep(const float* __restrict__ W1,
                                              const float* __restrict__ b1,
                                              const float* __restrict__ alpha,
                                              const float* __restrict__ W2,
                                              const float* __restrict__ b2,
                                              bf16_t* __restrict__ WT,
                                              float* __restrict__ wabsp,
                                              float* __restrict__ u1g,
                                              float* __restrict__ u2g,
                                              float* __restrict__ constg,
                                              float* __restrict__ acc_ws,
                                              unsigned int* __restrict__ ticket_ws) {
    __shared__ float w1L[128];
    int i = blockIdx.x * 256 + threadIdx.x;
    if (i < 32768) {
        int n = i >> 7;
        int k = i & 127;
        float v = (n < 128) ? W1[k * 128 + n] : W1[(k + 128) * 128 + (n - 128)];
        WT[i] = (bf16_t)v;
    }
    if (blockIdx.x == 128) {
        int t = threadIdx.x;
        if (t < 128) {
            float wd = W2[2 * t + 1] - W2[2 * t];
            float al = alpha[t];
            w1L[t] = wd * (1.f + al) * 0.5f;
            int c = (t & 7) * 16 + (t >> 3);          // permuted channel
            float wdc = W2[2 * c + 1] - W2[2 * c];
            wabsp[t] = wdc * (1.f - alpha[c]) * 0.5f;
        }
        __syncthreads();
        if (t < 128) {
            float a1 = 0.f, a2 = 0.f;
            for (int j = 0; j < 128; ++j) {
                a1 = fmaf(W1[t * 128 + j], w1L[j], a1);
                a2 = fmaf(W1[(t + 128) * 128 + j], w1L[j], a2);
            }
            u1g[t] = a1;
            u2g[t] = a2;
        }
        if (t == 128) {
            float c = 0.f;
            for (int j = 0; j < 128; ++j) c = fmaf(w1L[j], b1[j], c);
            *constg = c + (b2[1] - b2[0]);
        }
        if (t == 129) { *acc_ws = 0.f; *ticket_ws = 0u; }
    }
}

// ---------------- kernel 2: LDS-staged GEMM (64 rows x 256 cols per block) --
// A-tile bf16 in LDS, chunk index r*16 + (c ^ (r&7)) -> conflict-minimal
// ds_write (staging) AND ds_read_b128 (fragments). B double-buffered from WT.
__global__ __launch_bounds__(256) void k_gemm(const float* __restrict__ F,     // [100000,128]
                                              const bf16_t* __restrict__ WT,   // [256,128]
                                              const float* __restrict__ b1,
                                              const float* __restrict__ u1g,
                                              const float* __restrict__ u2g,
                                              const int* __restrict__ label,
                                              unsigned char* __restrict__ PQ8,
                                              float4* __restrict__ aux_g) {
    __shared__ bf16x8 Asm[1024];            // 16 KB
    const int t = threadIdx.x;
    const int m0 = blockIdx.x * 64;

    // ---- stage A: 1024 32-B f32 units -> bf16 16-B chunks, coalesced reads
#pragma unroll
    for (int j = 0; j < 4; ++j) {
        int unit = j * 256 + t;            // 0..1023
        int r = unit >> 4;                 // row 0..63
        int u = unit & 15;                 // 8-f32 unit within row
        int gr = m0 + r;
        float4 fa = {0.f, 0.f, 0.f, 0.f}, fb = {0.f, 0.f, 0.f, 0.f};
        if (gr < N_NODES) {
            const float4* src = (const float4*)(F + (size_t)gr * 128 + u * 8);
            fa = src[0]; fb = src[1];
        }
        bf16x8 v;
        v[0] = (bf16_t)fa.x; v[1] = (bf16_t)fa.y; v[2] = (bf16_t)fa.z; v[3] = (bf16_t)fa.w;
        v[4] = (bf16_t)fb.x; v[5] = (bf16_t)fb.y; v[6] = (bf16_t)fb.z; v[7] = (bf16_t)fb.w;
        Asm[r * 16 + (u ^ (r & 7))] = v;
    }
    __syncthreads();

    const int w = t >> 6, lane = t & 63;
    const int l15 = lane & 15, quad = lane >> 4;

    // B fragments: cols w*64 + nt*16 + l15, k-slice s*32 + quad*8
    const bf16_t* wbase = WT + (size_t)(w * 64 + l15) * 128 + quad * 8;

    floatx4 acc[4][4] = {};
    float a1 = 0.f, a2 = 0.f;
    bf16x8 Bf[2][4];
#pragma unroll
    for (int nt = 0; nt < 4; ++nt)
        Bf[0][nt] = *(const bf16x8*)(wbase + nt * 2048);

#pragma unroll
    for (int s = 0; s < 4; ++s) {
        if (s < 3) {
#pragma unroll
            for (int nt = 0; nt < 4; ++nt)
                Bf[(s + 1) & 1][nt] = *(const bf16x8*)(wbase + nt * 2048 + (s + 1) * 32);
        }
        bf16x8 Af[4];
#pragma unroll
        for (int mt = 0; mt < 4; ++mt) {
            int r = mt * 16 + l15;
            Af[mt] = Asm[r * 16 + ((s * 4 + quad) ^ (r & 7))];
        }
        // aux dot-products for this wave's own row group (mt == w)
        float4 ua = *(const float4*)(u1g + s * 32 + quad * 8);
        float4 ub = *(const float4*)(u1g + s * 32 + quad * 8 + 4);
        float4 va = *(const float4*)(u2g + s * 32 + quad * 8);
        float4 vb = *(const float4*)(u2g + s * 32 + quad * 8 + 4);
        bf16x8 aw = Af[w];
        a1 = fmaf((float)aw[0], ua.x, a1); a1 = fmaf((float)aw[1], ua.y, a1);
        a1 = fmaf((float)aw[2], ua.z, a1); a1 = fmaf((float)aw[3], ua.w, a1);
        a1 = fmaf((float)aw[4], ub.x, a1); a1 = fmaf((float)aw[5], ub.y, a1);
        a1 = fmaf((float)aw[6], ub.z, a1); a1 = fmaf((float)aw[7], ub.w, a1);
        a2 = fmaf((float)aw[0], va.x, a2); a2 = fmaf((float)aw[1], va.y, a2);
        a2 = fmaf((float)aw[2], va.z, a2); a2 = fmaf((float)aw[3], va.w, a2);
        a2 = fmaf((float)aw[4], vb.x, a2); a2 = fmaf((float)aw[5], vb.y, a2);
        a2 = fmaf((float)aw[6], vb.z, a2); a2 = fmaf((float)aw[7], vb.w, a2);
#pragma unroll
        for (int mt = 0; mt < 4; ++mt)
#pragma unroll
            for (int nt = 0; nt < 4; ++nt)
                acc[mt][nt] = __builtin_amdgcn_mfma_f32_16x16x32_bf16(Af[mt], Bf[s & 1][nt], acc[mt][nt], 0, 0, 0);
    }

    // aux: reduce over quads (same l15), lane quad==0 stores row m0+w*16+l15
    a1 += __shfl_xor(a1, 16, 64); a1 += __shfl_xor(a1, 32, 64);
    a2 += __shfl_xor(a2, 16, 64); a2 += __shfl_xor(a2, 32, 64);
    if (quad == 0) {
        int grow = m0 + w * 16 + l15;
        if (grow < N_NODES) {
            float4 av = {a1, a2, __int_as_float(label[grow]), 0.f};
            aux_g[grow] = av;
        }
    }

    // ---- epilogue: wave w covers j = (w&1)*4..+3 of half h = w>>1
    const int h = w >> 1, jb = (w & 1) * 4;
    float bv[4];
#pragma unroll
    for (int nt = 0; nt < 4; ++nt)
        bv[nt] = (h == 0) ? b1[(jb + nt) * 16 + l15] : 0.f;
#pragma unroll
    for (int mt = 0; mt < 4; ++mt) {
#pragma unroll
        for (int r = 0; r < 4; ++r) {
            int grow = m0 + mt * 16 + quad * 4 + r;
            if (grow < N_NODES) {
                unsigned int pk = 0;
                pk = __builtin_amdgcn_cvt_pk_fp8_f32(acc[mt][0][r] + bv[0], acc[mt][1][r] + bv[1], pk, false);
                pk = __builtin_amdgcn_cvt_pk_fp8_f32(acc[mt][2][r] + bv[2], acc[mt][3][r] + bv[3], pk, true);
                *(unsigned int*)(PQ8 + (size_t)grow * 256 + h * 128 + l15 * 8 + jb) = pk;
            }
        }
    }
}

// ---------------- kernel 3: per-edge loss, 16 lanes/edge, 8-edge ILP -------
__global__ __launch_bounds__(256) void k_edge_loss(const unsigned char* __restrict__ PQ8,
                                                   const float4* __restrict__ aux,
                                                   const float* __restrict__ wabsp,
                                                   const float* __restrict__ constg,
                                                   const int* __restrict__ row,
                                                   const int* __restrict__ col,
                                                   float* __restrict__ acc_ws,
                                                   unsigned int* __restrict__ ticket_ws,
                                                   float* __restrict__ out) {
    const int lg = threadIdx.x & 15;
    const int group = (blockIdx.x * blockDim.x + threadIdx.x) >> 4;
    const int ng = (gridDim.x * blockDim.x) >> 4;
    const int ch = lg * 8;

    float wabs[8];
#pragma unroll
    for (int j = 0; j < 8; ++j) wabs[j] = wabsp[ch + j];
    const float CB = *constg;

    float acc = 0.f;
    for (int e = group; e < N_EDGES; e += 8 * ng) {
        int r[8], c[8];
#pragma unroll
        for (int k = 0; k < 8; ++k) {
            int ee = e + k * ng;
            int es = (ee < N_EDGES) ? ee : e;
            r[k] = row[es]; c[k] = col[es];
        }
        uint2 p[8], q[8];
#pragma unroll
        for (int k = 0; k < 8; ++k) {
            p[k] = *(const uint2*)(PQ8 + (size_t)r[k] * 256 + ch);
            q[k] = *(const uint2*)(PQ8 + (size_t)c[k] * 256 + 128 + ch);
        }
        // per-lane aux: lanes 0-7 take edge lg's row-aux, lanes 8-15 edge (lg-8)'s col-aux
        int ee2 = e + (lg & 7) * ng;
        int es2 = (ee2 < N_EDGES) ? ee2 : e;
        const int* ibase = (lg < 8) ? row : col;
        float4 a = aux[ibase[es2]];

        float sab[8] = {0.f, 0.f, 0.f, 0.f, 0.f, 0.f, 0.f, 0.f};
#pragma unroll
        for (int k = 0; k < 8; ++k) {
            floatx2 p01 = __builtin_amdgcn_cvt_pk_f32_fp8((int)p[k].x, false);
            floatx2 p23 = __builtin_amdgcn_cvt_pk_f32_fp8((int)p[k].x, true);
            floatx2 p45 = __builtin_amdgcn_cvt_pk_f32_fp8((int)p[k].y, false);
            floatx2 p67 = __builtin_amdgcn_cvt_pk_f32_fp8((int)p[k].y, true);
            floatx2 q01 = __builtin_amdgcn_cvt_pk_f32_fp8((int)q[k].x, false);
            floatx2 q23 = __builtin_amdgcn_cvt_pk_f32_fp8((int)q[k].x, true);
            floatx2 q45 = __builtin_amdgcn_cvt_pk_f32_fp8((int)q[k].y, false);
            floatx2 q67 = __builtin_amdgcn_cvt_pk_f32_fp8((int)q[k].y, true);
            floatx2 h01 = p01 + q01;
            floatx2 h23 = p23 + q23;
            floatx2 h45 = p45 + q45;
            floatx2 h67 = p67 + q67;
            float s = sab[k];
            s = fmaf(fabsf(h01[0]), wabs[0], s);
            s = fmaf(fabsf(h01[1]), wabs[1], s);
            s = fmaf(fabsf(h23[0]), wabs[2], s);
            s = fmaf(fabsf(h23[1]), wabs[3], s);
            s = fmaf(fabsf(h45[0]), wabs[4], s);
            s = fmaf(fabsf(h45[1]), wabs[5], s);
            s = fmaf(fabsf(h67[0]), wabs[6], s);
            s = fmaf(fabsf(h67[1]), wabs[7], s);
            sab[k] = s;
        }
#pragma unroll
        for (int m = 8; m >= 1; m >>= 1) {
#pragma unroll
            for (int k = 0; k < 8; ++k) sab[k] += __shfl_xor(sab[k], m, 16);
        }
        // lanes 0-7 finish edge lg in parallel
        float s2o = __shfl(a.y, (lg + 8) & 15, 16);
        float lzc = __shfl(a.z, (lg + 8) & 15, 16);
        float mysab = sab[0];
#pragma unroll
        for (int k = 1; k < 8; ++k) mysab = (lg == k) ? sab[k] : mysab;
        float D = a.x + s2o + CB + mysab;
        float sgn = (__float_as_int(a.z) == __float_as_int(lzc)) ? -D : D;
        float loss = fmaxf(sgn, 0.f) + __logf(1.f + __expf(-fabsf(sgn)));
        bool vld = (lg < 8) && (e + lg * ng < N_EDGES);
        acc += vld ? loss : 0.f;
    }
#pragma unroll
    for (int m = 32; m >= 1; m >>= 1) acc += __shfl_xor(acc, m, 64);
    __shared__ float sdata[4];
    int lane = threadIdx.x & 63;
    int wv = threadIdx.x >> 6;
    if (lane == 0) sdata[wv] = acc;
    __syncthreads();
    if (threadIdx.x == 0) {
        float s = (sdata[0] + sdata[1]) + (sdata[2] + sdata[3]);
        atomicAdd(acc_ws, s);
        __threadfence();
        unsigned int tk = atomicAdd(ticket_ws, 1u);
        if (tk == gridDim.x - 1) {
            float tot = atomicAdd(acc_ws, 0.f);   // device-scope readback
            out[0] = tot * (1.f / (float)N_EDGES);
        }
    }
}

extern "C" void kernel_launch(void* const* d_in, const int* in_sizes, int n_in,
                              void* d_out, int out_size, void* d_ws, size_t ws_size,
                              hipStream_t stream) {
    const float* feature = (const float*)d_in[0];   // [100000,128]
    const float* W1      = (const float*)d_in[1];   // [256,128]
    const float* b1      = (const float*)d_in[2];   // [128]
    const float* alpha   = (const float*)d_in[3];   // [128]
    const float* W2      = (const float*)d_in[4];   // [128,2]
    const float* b2      = (const float*)d_in[5];   // [2]
    const int*   row     = (const int*)d_in[6];     // [1M]
    const int*   col     = (const int*)d_in[7];     // [1M]
    const int*   label   = (const int*)d_in[8];     // [100000]
    float* out = (float*)d_out;

    char* ws = (char*)d_ws;
    unsigned char* PQ8 = (unsigned char*)(ws);      // 25,600,000 B
    float4* aux  = (float4*)(ws + 25600000);        // 1,600,000 B
    bf16_t* WT   = (bf16_t*)(ws + 27200000);        // 65,536 B
    float* wabsp = (float*)(ws + 27265536);         // 512 B
    float* u1g   = (float*)(ws + 27266048);         // 512 B
    float* u2g   = (float*)(ws + 27266560);         // 512 B
    float* constg= (float*)(ws + 27267072);         // 4 B
    float* acc_ws= (float*)(ws + 27267076);         // 4 B
    unsigned int* ticket_ws = (unsigned int*)(ws + 27267080); // 4 B

    k_prep<<<129, 256, 0, stream>>>(W1, b1, alpha, W2, b2, WT, wabsp, u1g, u2g,
                                    constg, acc_ws, ticket_ws);
    k_gemm<<<1563, 256, 0, stream>>>(feature, WT, b1, u1g, u2g, label, PQ8, aux);
    k_edge_loss<<<2048, 256, 0, stream>>>(PQ8, aux, wabsp, constg, row, col,
                                          acc_ws, ticket_ws, out);
}

// Round 7
// 209.498 us; speedup vs baseline: 1.2865x; 1.2865x over previous
//
#include <hip/hip_runtime.h>
#include <hip/hip_bf16.h>

typedef __bf16 bf16_t;
typedef bf16_t bf16x8 __attribute__((ext_vector_type(8)));
typedef float floatx4 __attribute__((ext_vector_type(4)));
typedef float floatx2 __attribute__((ext_vector_type(2)));

#define N_NODES 100000
#define N_EDGES 1000000
#define N_TILES 6250

// PQ8 row layout (256 B per node): byte b = h*128 + l15*8 + j  holds fp8 of
// column  h*128 + j*16 + l15   (h = half, l15 = 0..15, j = 0..7).
// Edge kernel lane lg reads bytes lg*8..lg*8+7 of a half -> channels j*16+lg;
// identical mapping for p-half and q-half, wabs permuted to match.

// ---------------- kernel 1: prep ----------------
__global__ __launch_bounds__(256) void k_prep(const float* __restrict__ W1,
                                              const float* __restrict__ b1,
                                              const float* __restrict__ alpha,
                                              const float* __restrict__ W2,
                                              const float* __restrict__ b2,
                                              bf16_t* __restrict__ WT,
                                              float* __restrict__ wabsp,
                                              float* __restrict__ u1g,
                                              float* __restrict__ u2g,
                                              float* __restrict__ constg,
                                              float* __restrict__ out) {
    __shared__ float w1L[128];
    int i = blockIdx.x * 256 + threadIdx.x;
    if (i < 32768) {
        int n = i >> 7;
        int k = i & 127;
        float v = (n < 128) ? W1[k * 128 + n] : W1[(k + 128) * 128 + (n - 128)];
        WT[i] = (bf16_t)v;
    }
    if (blockIdx.x == 128) {
        int t = threadIdx.x;
        if (t < 128) {
            float wd = W2[2 * t + 1] - W2[2 * t];
            float al = alpha[t];
            w1L[t] = wd * (1.f + al) * 0.5f;
            int c = (t & 7) * 16 + (t >> 3);          // permuted channel
            float wdc = W2[2 * c + 1] - W2[2 * c];
            wabsp[t] = wdc * (1.f - alpha[c]) * 0.5f;
        }
        __syncthreads();
        if (t < 128) {
            float a1 = 0.f, a2 = 0.f;
            for (int j = 0; j < 128; ++j) {
                a1 = fmaf(W1[t * 128 + j], w1L[j], a1);
                a2 = fmaf(W1[(t + 128) * 128 + j], w1L[j], a2);
            }
            u1g[t] = a1;
            u2g[t] = a2;
        }
        if (t == 128) {
            float c = 0.f;
            for (int j = 0; j < 128; ++j) c = fmaf(w1L[j], b1[j], c);
            *constg = c + (b2[1] - b2[0]);
        }
        if (t == 129) out[0] = 0.f;       // zero the output accumulator (stream-ordered)
    }
}

// ---------------- kernel 2: persistent-wave GEMM, B resident in registers ---
// Wave w: cols w*64 .. w*64+63 (16 B-frags held in VGPRs for the whole kernel),
// grid-strides over 16-row tiles. No LDS, no barriers.
__global__ __launch_bounds__(256) void k_gemm(const float* __restrict__ F,     // [100000,128]
                                              const bf16_t* __restrict__ WT,   // [256,128]
                                              const float* __restrict__ b1,
                                              const float* __restrict__ u1g,
                                              const float* __restrict__ u2g,
                                              const int* __restrict__ label,
                                              unsigned char* __restrict__ PQ8,
                                              float4* __restrict__ aux_g) {
    const int w = threadIdx.x >> 6, lane = threadIdx.x & 63;
    const int l15 = lane & 15, quad = lane >> 4;
    const int h = w >> 1, jb = (w & 1) * 4;

    // resident B fragments: B[n = w*64 + nt*16 + l15][k = s*32 + quad*8 ..]
    bf16x8 Bf[4][4];
    const bf16_t* wbase = WT + (size_t)(w * 64 + l15) * 128 + quad * 8;
#pragma unroll
    for (int s = 0; s < 4; ++s)
#pragma unroll
        for (int nt = 0; nt < 4; ++nt)
            Bf[s][nt] = *(const bf16x8*)(wbase + (size_t)nt * 2048 + s * 32);

    float bv[4];
#pragma unroll
    for (int nt = 0; nt < 4; ++nt)
        bv[nt] = (h == 0) ? b1[(jb + nt) * 16 + l15] : 0.f;

    for (int tile = blockIdx.x; tile < N_TILES; tile += gridDim.x) {
        const int m0 = tile * 16;
        const float4* Ar = (const float4*)(F + (size_t)(m0 + l15) * 128 + quad * 8);
        // issue all 8 A-loads up front (independent, 8 in flight)
        float4 fa[4], fb[4];
#pragma unroll
        for (int s = 0; s < 4; ++s) { fa[s] = Ar[s * 8]; fb[s] = Ar[s * 8 + 1]; }

        bf16x8 Af[4];
#pragma unroll
        for (int s = 0; s < 4; ++s) {
            bf16x8 v;
            v[0] = (bf16_t)fa[s].x; v[1] = (bf16_t)fa[s].y;
            v[2] = (bf16_t)fa[s].z; v[3] = (bf16_t)fa[s].w;
            v[4] = (bf16_t)fb[s].x; v[5] = (bf16_t)fb[s].y;
            v[6] = (bf16_t)fb[s].z; v[7] = (bf16_t)fb[s].w;
            Af[s] = v;
        }

        floatx4 acc[4] = {};
#pragma unroll
        for (int s = 0; s < 4; ++s)
#pragma unroll
            for (int nt = 0; nt < 4; ++nt)
                acc[nt] = __builtin_amdgcn_mfma_f32_16x16x32_bf16(Af[s], Bf[s][nt], acc[nt], 0, 0, 0);

        // aux (wave 0 only): s1 = row.u1, s2 = row.u2 from the f32 registers
        if (w == 0) {
            float s1 = 0.f, s2 = 0.f;
#pragma unroll
            for (int s = 0; s < 4; ++s) {
                const float* u1p = u1g + s * 32 + quad * 8;
                const float* u2p = u2g + s * 32 + quad * 8;
                float fv[8] = {fa[s].x, fa[s].y, fa[s].z, fa[s].w,
                               fb[s].x, fb[s].y, fb[s].z, fb[s].w};
#pragma unroll
                for (int j = 0; j < 8; ++j) {
                    s1 = fmaf(fv[j], u1p[j], s1);
                    s2 = fmaf(fv[j], u2p[j], s2);
                }
            }
            s1 += __shfl_xor(s1, 16, 64); s1 += __shfl_xor(s1, 32, 64);
            s2 += __shfl_xor(s2, 16, 64); s2 += __shfl_xor(s2, 32, 64);
            if (quad == 0) {
                int grow = m0 + l15;
                float4 av = {s1, s2, __int_as_float(label[grow]), 0.f};
                aux_g[grow] = av;
            }
        }

        // epilogue: row = m0 + quad*4 + r, cols (jb+nt)*16 + l15 of half h
#pragma unroll
        for (int r = 0; r < 4; ++r) {
            int grow = m0 + quad * 4 + r;
            unsigned int pk = 0;
            pk = __builtin_amdgcn_cvt_pk_fp8_f32(acc[0][r] + bv[0], acc[1][r] + bv[1], pk, false);
            pk = __builtin_amdgcn_cvt_pk_fp8_f32(acc[2][r] + bv[2], acc[3][r] + bv[3], pk, true);
            *(unsigned int*)(PQ8 + (size_t)grow * 256 + h * 128 + l15 * 8 + jb) = pk;
        }
    }
}

// ---------------- kernel 3: per-edge loss, 16 lanes/edge, 8-edge ILP -------
__global__ __launch_bounds__(256) void k_edge_loss(const unsigned char* __restrict__ PQ8,
                                                   const float4* __restrict__ aux,
                                                   const float* __restrict__ wabsp,
                                                   const float* __restrict__ constg,
                                                   const int* __restrict__ row,
                                                   const int* __restrict__ col,
                                                   float* __restrict__ out) {
    const int lg = threadIdx.x & 15;
    const int group = (blockIdx.x * blockDim.x + threadIdx.x) >> 4;
    const int ng = (gridDim.x * blockDim.x) >> 4;
    const int ch = lg * 8;

    float wabs[8];
#pragma unroll
    for (int j = 0; j < 8; ++j) wabs[j] = wabsp[ch + j];
    const float CB = *constg;

    float acc = 0.f;
    for (int e = group; e < N_EDGES; e += 8 * ng) {
        int r[8], c[8];
#pragma unroll
        for (int k = 0; k < 8; ++k) {
            int ee = e + k * ng;
            int es = (ee < N_EDGES) ? ee : e;
            r[k] = row[es]; c[k] = col[es];
        }
        uint2 p[8], q[8];
#pragma unroll
        for (int k = 0; k < 8; ++k) {
            p[k] = *(const uint2*)(PQ8 + (size_t)r[k] * 256 + ch);
            q[k] = *(const uint2*)(PQ8 + (size_t)c[k] * 256 + 128 + ch);
        }
        // per-lane aux: lanes 0-7 take edge lg's row-aux, lanes 8-15 edge (lg-8)'s col-aux
        int ee2 = e + (lg & 7) * ng;
        int es2 = (ee2 < N_EDGES) ? ee2 : e;
        const int* ibase = (lg < 8) ? row : col;
        float4 a = aux[ibase[es2]];

        float sab[8] = {0.f, 0.f, 0.f, 0.f, 0.f, 0.f, 0.f, 0.f};
#pragma unroll
        for (int k = 0; k < 8; ++k) {
            floatx2 p01 = __builtin_amdgcn_cvt_pk_f32_fp8((int)p[k].x, false);
            floatx2 p23 = __builtin_amdgcn_cvt_pk_f32_fp8((int)p[k].x, true);
            floatx2 p45 = __builtin_amdgcn_cvt_pk_f32_fp8((int)p[k].y, false);
            floatx2 p67 = __builtin_amdgcn_cvt_pk_f32_fp8((int)p[k].y, true);
            floatx2 q01 = __builtin_amdgcn_cvt_pk_f32_fp8((int)q[k].x, false);
            floatx2 q23 = __builtin_amdgcn_cvt_pk_f32_fp8((int)q[k].x, true);
            floatx2 q45 = __builtin_amdgcn_cvt_pk_f32_fp8((int)q[k].y, false);
            floatx2 q67 = __builtin_amdgcn_cvt_pk_f32_fp8((int)q[k].y, true);
            floatx2 h01 = p01 + q01;
            floatx2 h23 = p23 + q23;
            floatx2 h45 = p45 + q45;
            floatx2 h67 = p67 + q67;
            float s = sab[k];
            s = fmaf(fabsf(h01[0]), wabs[0], s);
            s = fmaf(fabsf(h01[1]), wabs[1], s);
            s = fmaf(fabsf(h23[0]), wabs[2], s);
            s = fmaf(fabsf(h23[1]), wabs[3], s);
            s = fmaf(fabsf(h45[0]), wabs[4], s);
            s = fmaf(fabsf(h45[1]), wabs[5], s);
            s = fmaf(fabsf(h67[0]), wabs[6], s);
            s = fmaf(fabsf(h67[1]), wabs[7], s);
            sab[k] = s;
        }
#pragma unroll
        for (int m = 8; m >= 1; m >>= 1) {
#pragma unroll
            for (int k = 0; k < 8; ++k) sab[k] += __shfl_xor(sab[k], m, 16);
        }
        // lanes 0-7 finish edge lg in parallel
        float s2o = __shfl(a.y, (lg + 8) & 15, 16);
        float lzc = __shfl(a.z, (lg + 8) & 15, 16);
        float mysab = sab[0];
#pragma unroll
        for (int k = 1; k < 8; ++k) mysab = (lg == k) ? sab[k] : mysab;
        float D = a.x + s2o + CB + mysab;
        float sgn = (__float_as_int(a.z) == __float_as_int(lzc)) ? -D : D;
        float loss = fmaxf(sgn, 0.f) + __logf(1.f + __expf(-fabsf(sgn)));
        bool vld = (lg < 8) && (e + lg * ng < N_EDGES);
        acc += vld ? loss : 0.f;
    }
#pragma unroll
    for (int m = 32; m >= 1; m >>= 1) acc += __shfl_xor(acc, m, 64);
    __shared__ float sdata[4];
    int lane = threadIdx.x & 63;
    int wv = threadIdx.x >> 6;
    if (lane == 0) sdata[wv] = acc;
    __syncthreads();
    if (threadIdx.x == 0) {
        float s = (sdata[0] + sdata[1]) + (sdata[2] + sdata[3]);
        atomicAdd(out, s * (1.f / (float)N_EDGES));
    }
}

extern "C" void kernel_launch(void* const* d_in, const int* in_sizes, int n_in,
                              void* d_out, int out_size, void* d_ws, size_t ws_size,
                              hipStream_t stream) {
    const float* feature = (const float*)d_in[0];   // [100000,128]
    const float* W1      = (const float*)d_in[1];   // [256,128]
    const float* b1      = (const float*)d_in[2];   // [128]
    const float* alpha   = (const float*)d_in[3];   // [128]
    const float* W2      = (const float*)d_in[4];   // [128,2]
    const float* b2      = (const float*)d_in[5];   // [2]
    const int*   row     = (const int*)d_in[6];     // [1M]
    const int*   col     = (const int*)d_in[7];     // [1M]
    const int*   label   = (const int*)d_in[8];     // [100000]
    float* out = (float*)d_out;

    char* ws = (char*)d_ws;
    unsigned char* PQ8 = (unsigned char*)(ws);      // 25,600,000 B
    float4* aux  = (float4*)(ws + 25600000);        // 1,600,000 B
    bf16_t* WT   = (bf16_t*)(ws + 27200000);        // 65,536 B
    float* wabsp = (float*)(ws + 27265536);         // 512 B
    float* u1g   = (float*)(ws + 27266048);         // 512 B
    float* u2g   = (float*)(ws + 27266560);         // 512 B
    float* constg= (float*)(ws + 27267072);         // 4 B

    k_prep<<<129, 256, 0, stream>>>(W1, b1, alpha, W2, b2, WT, wabsp, u1g, u2g,
                                    constg, out);
    k_gemm<<<1024, 256, 0, stream>>>(feature, WT, b1, u1g, u2g, label, PQ8, aux);
    k_edge_loss<<<4096, 256, 0, stream>>>(PQ8, aux, wabsp, constg, row, col, out);
}